// Round 1
// baseline (660.348 us; speedup 1.0000x reference)
//
#include <hip/hip_runtime.h>
#include <hip/hip_bf16.h>

// SparseMoE: N=2048 tokens, D_IN=1024, D_HID=4096, D_OUT=1024, E=8, top-K=2.
// Sparse path: gate -> route/compact (128-padded per expert) -> grouped GEMM1
// (relu) -> grouped GEMM2 -> weighted combine. GEMMs: bf16 MFMA 16x16x32,
// 128x128 tile, BK=32, A via global_load_lds(16B), W fp32->bf16 in staging.

#define N_TOK   2048
#define D_IN    1024
#define D_HID   4096
#define D_OUT   1024
#define NEXP    8
#define TOPK    2
#define ROW_CAP 5120   // max padded rows: 4096 + 8*127 = 5112, round up

typedef __bf16 bf16x8 __attribute__((ext_vector_type(8)));
typedef float  f32x4  __attribute__((ext_vector_type(4)));

__device__ inline unsigned short f2bf(float f) {
    union { float f; unsigned u; } v; v.f = f;
    unsigned u = v.u;
    return (unsigned short)((u + 0x7FFFu + ((u >> 16) & 1u)) >> 16);  // RNE
}
__device__ inline unsigned pack2(float lo, float hi) {
    return (unsigned)f2bf(lo) | ((unsigned)f2bf(hi) << 16);
}
__device__ inline void async_copy16(const void* g, void* l) {
    __builtin_amdgcn_global_load_lds(
        (const __attribute__((address_space(1))) void*)g,
        (__attribute__((address_space(3))) void*)l, 16, 0, 0);
}

// ---------------- gate: 1 wave per token ----------------
__global__ __launch_bounds__(256) void gate_kernel(
    const float* __restrict__ x, const float* __restrict__ gw,
    const float* __restrict__ gb, int* __restrict__ topi,
    float* __restrict__ topw, int* __restrict__ counts)
{
    int wave = threadIdx.x >> 6, lane = threadIdx.x & 63;
    int t = blockIdx.x * 4 + wave;
    const float* xt = x + (size_t)t * D_IN;
    float acc[NEXP];
#pragma unroll
    for (int e = 0; e < NEXP; e++) acc[e] = 0.f;
    for (int i = 0; i < D_IN / 64; i++) {
        float xv = xt[lane + 64 * i];
#pragma unroll
        for (int e = 0; e < NEXP; e++)
            acc[e] += xv * gw[e * D_IN + lane + 64 * i];
    }
#pragma unroll
    for (int e = 0; e < NEXP; e++) {
        float v = acc[e];
#pragma unroll
        for (int m = 32; m; m >>= 1) v += __shfl_xor(v, m, 64);
        acc[e] = v + gb[e];
    }
    if (lane == 0) {
        float b1v = -1e30f; int i1 = 0;
#pragma unroll
        for (int e = 0; e < NEXP; e++) if (acc[e] > b1v) { b1v = acc[e]; i1 = e; }
        float b2v = -1e30f; int i2 = 0;
#pragma unroll
        for (int e = 0; e < NEXP; e++) if (e != i1 && acc[e] > b2v) { b2v = acc[e]; i2 = e; }
        float e2 = __expf(b2v - b1v);
        float inv = 1.f / (1.f + e2);
        topi[t * 2] = i1; topi[t * 2 + 1] = i2;
        topw[t * 2] = inv; topw[t * 2 + 1] = e2 * inv;
        atomicAdd(&counts[i1], 1);
        atomicAdd(&counts[i2], 1);
    }
}

// ---------------- scan: 128-padded exclusive prefix (E=8, trivial) ---------
__global__ void scan_kernel(const int* __restrict__ counts,
                            int* __restrict__ offsets, int* __restrict__ cursor)
{
    if (threadIdx.x == 0 && blockIdx.x == 0) {
        int off = 0;
        for (int e = 0; e < NEXP; e++) {
            offsets[e] = off;
            cursor[e]  = off;
            off += (counts[e] + 127) & ~127;
        }
    }
}

// ---------------- gather: one wave per (token, k) slot ----------------
__global__ __launch_bounds__(64) void gather_kernel(
    const float* __restrict__ x, const int* __restrict__ topi,
    int* __restrict__ cursor, int* __restrict__ slot_of,
    unsigned short* __restrict__ Xe)
{
    int b = blockIdx.x;          // 0..N*TOPK-1
    int t = b >> 1;
    __shared__ int spos;
    if (threadIdx.x == 0) {
        int e = topi[b];
        int pos = atomicAdd(&cursor[e], 1);
        slot_of[b] = pos;
        spos = pos;
    }
    __syncthreads();
    int pos = spos;
    const float* src = x + (size_t)t * D_IN;
    unsigned short* dst = Xe + (size_t)pos * D_IN;
    int l = threadIdx.x;
#pragma unroll
    for (int i = 0; i < 4; i++) {
        float4 f = *(const float4*)(src + l * 4 + i * 256);
        uint2 p; p.x = pack2(f.x, f.y); p.y = pack2(f.z, f.w);
        *(uint2*)(dst + l * 4 + i * 256) = p;
    }
}

// ---------------- grouped GEMM: C = act(A @ W[e]^T + bias[e]) --------------
// A: [rows, K] bf16 (row-major). W: [E, N, K] fp32. Out: [rows, N].
// Tile 128x128, BK=32, 256 threads = 4 waves, each wave 4x4 of 16x16x32 MFMA.
template <int KDIM, int NDIM, bool RELU, bool OUT_BF16>
__global__ __launch_bounds__(256) void moe_gemm(
    const unsigned short* __restrict__ A, const float* __restrict__ W,
    const float* __restrict__ bias, void* __restrict__ Out,
    const int* __restrict__ counts, const int* __restrict__ offsets)
{
    int e = blockIdx.z;
    int cnt = counts[e];
    int tm = blockIdx.y;
    if (tm * 128 >= cnt) return;
    int m0 = offsets[e] + tm * 128;
    int n0 = blockIdx.x * 128;

    __shared__ __align__(16) unsigned short As[128 * 32];
    __shared__ __align__(16) unsigned short Bs[128 * 32];

    int tid = threadIdx.x;
    int wave = tid >> 6, lane = tid & 63;

    const float* We = W + (size_t)e * NDIM * KDIM;

    f32x4 acc[4][4];
#pragma unroll
    for (int i = 0; i < 4; i++)
#pragma unroll
        for (int j = 0; j < 4; j++) acc[i][j] = (f32x4){0.f, 0.f, 0.f, 0.f};

    int m_off = (wave & 1) * 64;
    int n_off = (wave >> 1) * 64;

    // A staging: segment s covers rows 16s..16s+15, LDS bytes [s*1024, +1024)
    int arow0 = wave * 16 + (lane >> 2);
    int arow1 = (wave + 4) * 16 + (lane >> 2);
    int acolb = (lane & 3) * 16;               // byte offset in 64B row chunk
    // B staging: 2 threads per row, 16 fp32 each
    int brow = tid >> 1;
    int bcolf = (tid & 1) * 16;                // fp32 element offset

    for (int k0 = 0; k0 < KDIM; k0 += 32) {
        // --- A: global -> LDS, async 16B/lane ---
        {
            const char* g0 = (const char*)(A + (size_t)(m0 + arow0) * KDIM) + k0 * 2 + acolb;
            const char* g1 = (const char*)(A + (size_t)(m0 + arow1) * KDIM) + k0 * 2 + acolb;
            async_copy16(g0, (char*)As + wave * 1024);
            async_copy16(g1, (char*)As + (wave + 4) * 1024);
        }
        // --- B: fp32 global -> bf16 LDS ---
        {
            const float* src = We + (size_t)(n0 + brow) * KDIM + k0 + bcolf;
            float4 f0 = *(const float4*)(src);
            float4 f1 = *(const float4*)(src + 4);
            float4 f2 = *(const float4*)(src + 8);
            float4 f3 = *(const float4*)(src + 12);
            uint4 p0, p1;
            p0.x = pack2(f0.x, f0.y); p0.y = pack2(f0.z, f0.w);
            p0.z = pack2(f1.x, f1.y); p0.w = pack2(f1.z, f1.w);
            p1.x = pack2(f2.x, f2.y); p1.y = pack2(f2.z, f2.w);
            p1.z = pack2(f3.x, f3.y); p1.w = pack2(f3.z, f3.w);
            *(uint4*)&Bs[brow * 32 + bcolf]     = p0;
            *(uint4*)&Bs[brow * 32 + bcolf + 8] = p1;
        }
        __syncthreads();   // drains vmcnt (incl. global_load_lds) + lgkmcnt

        bf16x8 af[4], bfr[4];
#pragma unroll
        for (int mi = 0; mi < 4; mi++) {
            int r = m_off + mi * 16 + (lane & 15);
            af[mi] = *(const bf16x8*)&As[r * 32 + (lane >> 4) * 8];
        }
#pragma unroll
        for (int ni = 0; ni < 4; ni++) {
            int r = n_off + ni * 16 + (lane & 15);
            bfr[ni] = *(const bf16x8*)&Bs[r * 32 + (lane >> 4) * 8];
        }
#pragma unroll
        for (int mi = 0; mi < 4; mi++)
#pragma unroll
            for (int ni = 0; ni < 4; ni++)
                acc[mi][ni] = __builtin_amdgcn_mfma_f32_16x16x32_bf16(
                    af[mi], bfr[ni], acc[mi][ni], 0, 0, 0);

        __syncthreads();
    }

    // --- epilogue: C/D map col=lane&15, row=(lane>>4)*4+r ---
    const float* be = bias + (size_t)e * NDIM;
#pragma unroll
    for (int ni = 0; ni < 4; ni++) {
        int col = n0 + n_off + ni * 16 + (lane & 15);
        float bv = be[col];
#pragma unroll
        for (int mi = 0; mi < 4; mi++) {
            int row = m0 + m_off + mi * 16 + ((lane >> 4) * 4);
#pragma unroll
            for (int r2 = 0; r2 < 4; r2++) {
                float v = acc[mi][ni][r2] + bv;
                if (RELU) v = fmaxf(v, 0.f);
                if (OUT_BF16)
                    ((unsigned short*)Out)[(size_t)(row + r2) * NDIM + col] = f2bf(v);
                else
                    ((float*)Out)[(size_t)(row + r2) * NDIM + col] = v;
            }
        }
    }
}

// ---------------- combine: out[t] = w0*Y[s0] + w1*Y[s1] ----------------
__global__ __launch_bounds__(256) void combine_kernel(
    const float* __restrict__ Y, const int* __restrict__ slot_of,
    const float* __restrict__ topw, float* __restrict__ out)
{
    int t = blockIdx.x;
    int s0 = slot_of[t * 2], s1 = slot_of[t * 2 + 1];
    float w0 = topw[t * 2], w1 = topw[t * 2 + 1];
    int i = threadIdx.x;
    float4 y0 = *(const float4*)(Y + (size_t)s0 * D_OUT + i * 4);
    float4 y1 = *(const float4*)(Y + (size_t)s1 * D_OUT + i * 4);
    float4 o;
    o.x = w0 * y0.x + w1 * y1.x;
    o.y = w0 * y0.y + w1 * y1.y;
    o.z = w0 * y0.z + w1 * y1.z;
    o.w = w0 * y0.w + w1 * y1.w;
    *(float4*)(out + (size_t)t * D_OUT + i * 4) = o;
}

extern "C" void kernel_launch(void* const* d_in, const int* in_sizes, int n_in,
                              void* d_out, int out_size, void* d_ws, size_t ws_size,
                              hipStream_t stream)
{
    const float* x  = (const float*)d_in[0];
    const float* gw = (const float*)d_in[1];
    const float* gb = (const float*)d_in[2];
    const float* W1 = (const float*)d_in[3];
    const float* b1 = (const float*)d_in[4];
    const float* W2 = (const float*)d_in[5];
    const float* b2 = (const float*)d_in[6];
    float* out = (float*)d_out;

    char* ws = (char*)d_ws;
    int* counts  = (int*)ws;                 // 8 ints  @ [0,32)
    int* cursor  = counts + 8;               // 8 ints  @ [32,64)
    int* offsets = counts + 16;              // 8 ints  @ [64,96)
    int* topi    = counts + 32;              // 4096 ints
    int* slot_of = counts + 32 + 4096;       // 4096 ints
    float* topw  = (float*)(counts + 32 + 8192);  // 4096 floats (< 64 KB total)

    const size_t XE_OFF = 1ull << 16;
    const size_t H_OFF  = XE_OFF + (size_t)ROW_CAP * D_IN * 2;    // +10.0 MB
    const size_t Y_OFF  = H_OFF  + (size_t)ROW_CAP * D_HID * 2;   // +40.0 MB
    unsigned short* Xe = (unsigned short*)(ws + XE_OFF);
    unsigned short* H  = (unsigned short*)(ws + H_OFF);
    float*          Y  = (float*)(ws + Y_OFF);                    // +20.0 MB

    hipMemsetAsync(d_ws, 0, 128, stream);  // counts + cursor

    gate_kernel<<<N_TOK / 4, 256, 0, stream>>>(x, gw, gb, topi, topw, counts);
    scan_kernel<<<1, 64, 0, stream>>>(counts, offsets, cursor);
    gather_kernel<<<N_TOK * TOPK, 64, 0, stream>>>(x, topi, cursor, slot_of, Xe);

    moe_gemm<D_IN, D_HID, true, true><<<dim3(D_HID / 128, 16, NEXP), 256, 0, stream>>>(
        Xe, W1, b1, (void*)H, counts, offsets);
    moe_gemm<D_HID, D_OUT, false, false><<<dim3(D_OUT / 128, 16, NEXP), 256, 0, stream>>>(
        H, W2, b2, (void*)Y, counts, offsets);

    combine_kernel<<<N_TOK, 256, 0, stream>>>(Y, slot_of, topw, out);
}

// Round 2
// 584.213 us; speedup vs baseline: 1.1303x; 1.1303x over previous
//
#include <hip/hip_runtime.h>
#include <hip/hip_bf16.h>

// SparseMoE: N=2048, D_IN=1024, D_HID=4096, D_OUT=1024, E=8, K=2.
// R2: pre-convert W1/W2 fp32->bf16 (one pass), pure-bf16 m97-structure GEMMs
// (A and B both via global_load_lds width=16), split-K=4 for GEMM2 with
// fp32 atomicAdd partials (b2 folded into combine).

#define N_TOK   2048
#define D_IN    1024
#define D_HID   4096
#define D_OUT   1024
#define NEXP    8
#define TOPK    2
#define ROW_CAP 5120   // max padded rows: 4096 + 8*127 = 5112, round up

typedef __bf16 bf16x8 __attribute__((ext_vector_type(8)));
typedef float  f32x4  __attribute__((ext_vector_type(4)));

__device__ inline unsigned short f2bf(float f) {
    union { float f; unsigned u; } v; v.f = f;
    unsigned u = v.u;
    return (unsigned short)((u + 0x7FFFu + ((u >> 16) & 1u)) >> 16);  // RNE
}
__device__ inline unsigned pack2(float lo, float hi) {
    return (unsigned)f2bf(lo) | ((unsigned)f2bf(hi) << 16);
}
__device__ inline void async_copy16(const void* g, void* l) {
    __builtin_amdgcn_global_load_lds(
        (const __attribute__((address_space(1))) void*)g,
        (__attribute__((address_space(3))) void*)l, 16, 0, 0);
}

// ---------------- weight convert: fp32 -> bf16, grid-stride ----------------
__global__ __launch_bounds__(256) void convert_w(
    const float4* __restrict__ src, uint2* __restrict__ dst, int n4)
{
    int idx = blockIdx.x * 256 + threadIdx.x;
    int stride = gridDim.x * 256;
    for (int i = idx; i < n4; i += stride) {
        float4 f = src[i];
        uint2 p; p.x = pack2(f.x, f.y); p.y = pack2(f.z, f.w);
        dst[i] = p;
    }
}

// ---------------- gate: 1 wave per token ----------------
__global__ __launch_bounds__(256) void gate_kernel(
    const float* __restrict__ x, const float* __restrict__ gw,
    const float* __restrict__ gb, int* __restrict__ topi,
    float* __restrict__ topw, int* __restrict__ counts)
{
    int wave = threadIdx.x >> 6, lane = threadIdx.x & 63;
    int t = blockIdx.x * 4 + wave;
    const float* xt = x + (size_t)t * D_IN;
    float acc[NEXP];
#pragma unroll
    for (int e = 0; e < NEXP; e++) acc[e] = 0.f;
    for (int i = 0; i < D_IN / 64; i++) {
        float xv = xt[lane + 64 * i];
#pragma unroll
        for (int e = 0; e < NEXP; e++)
            acc[e] += xv * gw[e * D_IN + lane + 64 * i];
    }
#pragma unroll
    for (int e = 0; e < NEXP; e++) {
        float v = acc[e];
#pragma unroll
        for (int m = 32; m; m >>= 1) v += __shfl_xor(v, m, 64);
        acc[e] = v + gb[e];
    }
    if (lane == 0) {
        float b1v = -1e30f; int i1 = 0;
#pragma unroll
        for (int e = 0; e < NEXP; e++) if (acc[e] > b1v) { b1v = acc[e]; i1 = e; }
        float b2v = -1e30f; int i2 = 0;
#pragma unroll
        for (int e = 0; e < NEXP; e++) if (e != i1 && acc[e] > b2v) { b2v = acc[e]; i2 = e; }
        float e2 = __expf(b2v - b1v);
        float inv = 1.f / (1.f + e2);
        topi[t * 2] = i1; topi[t * 2 + 1] = i2;
        topw[t * 2] = inv; topw[t * 2 + 1] = e2 * inv;
        atomicAdd(&counts[i1], 1);
        atomicAdd(&counts[i2], 1);
    }
}

// ---------------- scan: 128-padded exclusive prefix ----------------
__global__ void scan_kernel(const int* __restrict__ counts,
                            int* __restrict__ offsets, int* __restrict__ cursor)
{
    if (threadIdx.x == 0 && blockIdx.x == 0) {
        int off = 0;
        for (int e = 0; e < NEXP; e++) {
            offsets[e] = off;
            cursor[e]  = off;
            off += (counts[e] + 127) & ~127;
        }
    }
}

// ---------------- gather: one wave per (token, k) slot ----------------
__global__ __launch_bounds__(64) void gather_kernel(
    const float* __restrict__ x, const int* __restrict__ topi,
    int* __restrict__ cursor, int* __restrict__ slot_of,
    unsigned short* __restrict__ Xe)
{
    int b = blockIdx.x;          // 0..N*TOPK-1
    int t = b >> 1;
    __shared__ int spos;
    if (threadIdx.x == 0) {
        int e = topi[b];
        int pos = atomicAdd(&cursor[e], 1);
        slot_of[b] = pos;
        spos = pos;
    }
    __syncthreads();
    int pos = spos;
    const float* src = x + (size_t)t * D_IN;
    unsigned short* dst = Xe + (size_t)pos * D_IN;
    int l = threadIdx.x;
#pragma unroll
    for (int i = 0; i < 4; i++) {
        float4 f = *(const float4*)(src + l * 4 + i * 256);
        uint2 p; p.x = pack2(f.x, f.y); p.y = pack2(f.z, f.w);
        *(uint2*)(dst + l * 4 + i * 256) = p;
    }
}

// ---------------- grouped GEMM (pure bf16, m97 structure) ------------------
// A: [rows, KDIM] bf16. Wb: [E, NDIM, KDIM] bf16. Tile 128x128, BK=32,
// 4 waves x (4x4) 16x16x32 MFMA. SPLITK chunks the K-loop across blockIdx.z.
// OUT_MODE: 0 = fp32 store (+bias), 1 = bf16 store (+bias), 2 = fp32 atomicAdd
template <int KDIM, int NDIM, int SPLITK, bool RELU, int OUT_MODE>
__global__ __launch_bounds__(256) void moe_gemm(
    const unsigned short* __restrict__ A, const unsigned short* __restrict__ Wb,
    const float* __restrict__ bias, void* __restrict__ Out,
    const int* __restrict__ counts, const int* __restrict__ offsets)
{
    constexpr int KCHUNK = KDIM / SPLITK;
    int e  = blockIdx.z / SPLITK;
    int kc = blockIdx.z % SPLITK;
    int cnt = counts[e];
    int tm = blockIdx.y;
    if (tm * 128 >= cnt) return;
    int m0 = offsets[e] + tm * 128;
    int n0 = blockIdx.x * 128;

    __shared__ __align__(16) unsigned short As[128 * 32];
    __shared__ __align__(16) unsigned short Bs[128 * 32];

    int tid = threadIdx.x;
    int wave = tid >> 6, lane = tid & 63;

    const unsigned short* We = Wb + (size_t)e * NDIM * KDIM;

    f32x4 acc[4][4];
#pragma unroll
    for (int i = 0; i < 4; i++)
#pragma unroll
        for (int j = 0; j < 4; j++) acc[i][j] = (f32x4){0.f, 0.f, 0.f, 0.f};

    int m_off = (wave & 1) * 64;
    int n_off = (wave >> 1) * 64;

    // staging: segment s covers rows 16s..16s+15, LDS bytes [s*1024, +1024)
    // lane -> row = seg*16 + (lane>>2), 16B chunk = (lane&3)*16 bytes
    int srow = lane >> 2;
    int scolb = (lane & 3) * 16;

    for (int k0 = kc * KCHUNK; k0 < kc * KCHUNK + KCHUNK; k0 += 32) {
        // A: global -> LDS, 2 issues/wave (segments wave, wave+4)
        {
            const char* g0 = (const char*)(A + (size_t)(m0 + wave * 16 + srow) * KDIM) + k0 * 2 + scolb;
            const char* g1 = (const char*)(A + (size_t)(m0 + (wave + 4) * 16 + srow) * KDIM) + k0 * 2 + scolb;
            async_copy16(g0, (char*)As + wave * 1024);
            async_copy16(g1, (char*)As + (wave + 4) * 1024);
        }
        // B: global -> LDS, 2 issues/wave
        {
            const char* g0 = (const char*)(We + (size_t)(n0 + wave * 16 + srow) * KDIM) + k0 * 2 + scolb;
            const char* g1 = (const char*)(We + (size_t)(n0 + (wave + 4) * 16 + srow) * KDIM) + k0 * 2 + scolb;
            async_copy16(g0, (char*)Bs + wave * 1024);
            async_copy16(g1, (char*)Bs + (wave + 4) * 1024);
        }
        __syncthreads();   // drains vmcnt (global_load_lds) before reads

        bf16x8 af[4], bfr[4];
#pragma unroll
        for (int mi = 0; mi < 4; mi++) {
            int r = m_off + mi * 16 + (lane & 15);
            af[mi] = *(const bf16x8*)&As[r * 32 + (lane >> 4) * 8];
        }
#pragma unroll
        for (int ni = 0; ni < 4; ni++) {
            int r = n_off + ni * 16 + (lane & 15);
            bfr[ni] = *(const bf16x8*)&Bs[r * 32 + (lane >> 4) * 8];
        }
#pragma unroll
        for (int mi = 0; mi < 4; mi++)
#pragma unroll
            for (int ni = 0; ni < 4; ni++)
                acc[mi][ni] = __builtin_amdgcn_mfma_f32_16x16x32_bf16(
                    af[mi], bfr[ni], acc[mi][ni], 0, 0, 0);

        __syncthreads();
    }

    // epilogue: C/D map col=lane&15, row=(lane>>4)*4+r
#pragma unroll
    for (int ni = 0; ni < 4; ni++) {
        int col = n0 + n_off + ni * 16 + (lane & 15);
        float bv = (OUT_MODE == 2) ? 0.f : bias[(size_t)e * NDIM + col];
#pragma unroll
        for (int mi = 0; mi < 4; mi++) {
            int row = m0 + m_off + mi * 16 + ((lane >> 4) * 4);
#pragma unroll
            for (int r2 = 0; r2 < 4; r2++) {
                float v = acc[mi][ni][r2] + bv;
                if (RELU) v = fmaxf(v, 0.f);
                if (OUT_MODE == 1)
                    ((unsigned short*)Out)[(size_t)(row + r2) * NDIM + col] = f2bf(v);
                else if (OUT_MODE == 0)
                    ((float*)Out)[(size_t)(row + r2) * NDIM + col] = v;
                else
                    atomicAdd(&((float*)Out)[(size_t)(row + r2) * NDIM + col], v);
            }
        }
    }
}

// ---------------- combine: out[t] = w0*(Y[s0]+b2[e0]) + w1*(Y[s1]+b2[e1]) --
__global__ __launch_bounds__(256) void combine_kernel(
    const float* __restrict__ Y, const int* __restrict__ slot_of,
    const int* __restrict__ topi, const float* __restrict__ topw,
    const float* __restrict__ b2, float* __restrict__ out)
{
    int t = blockIdx.x;
    int s0 = slot_of[t * 2], s1 = slot_of[t * 2 + 1];
    int e0 = topi[t * 2],    e1 = topi[t * 2 + 1];
    float w0 = topw[t * 2],  w1 = topw[t * 2 + 1];
    int i = threadIdx.x;
    float4 y0 = *(const float4*)(Y + (size_t)s0 * D_OUT + i * 4);
    float4 y1 = *(const float4*)(Y + (size_t)s1 * D_OUT + i * 4);
    float4 c0 = *(const float4*)(b2 + (size_t)e0 * D_OUT + i * 4);
    float4 c1 = *(const float4*)(b2 + (size_t)e1 * D_OUT + i * 4);
    float4 o;
    o.x = w0 * (y0.x + c0.x) + w1 * (y1.x + c1.x);
    o.y = w0 * (y0.y + c0.y) + w1 * (y1.y + c1.y);
    o.z = w0 * (y0.z + c0.z) + w1 * (y1.z + c1.z);
    o.w = w0 * (y0.w + c0.w) + w1 * (y1.w + c1.w);
    *(float4*)(out + (size_t)t * D_OUT + i * 4) = o;
}

extern "C" void kernel_launch(void* const* d_in, const int* in_sizes, int n_in,
                              void* d_out, int out_size, void* d_ws, size_t ws_size,
                              hipStream_t stream)
{
    const float* x  = (const float*)d_in[0];
    const float* gw = (const float*)d_in[1];
    const float* gb = (const float*)d_in[2];
    const float* W1 = (const float*)d_in[3];
    const float* b1 = (const float*)d_in[4];
    const float* W2 = (const float*)d_in[5];
    const float* b2 = (const float*)d_in[6];
    float* out = (float*)d_out;

    char* ws = (char*)d_ws;
    int* counts  = (int*)ws;                 // 8 ints
    int* cursor  = counts + 8;               // 8 ints
    int* offsets = counts + 16;              // 8 ints
    int* topi    = counts + 32;              // 4096 ints
    int* slot_of = counts + 32 + 4096;       // 4096 ints
    float* topw  = (float*)(counts + 32 + 8192);  // 4096 floats

    const size_t XE_OFF  = 1ull << 16;
    const size_t H_OFF   = XE_OFF  + (size_t)ROW_CAP * D_IN  * 2;  // +10.5 MB
    const size_t Y_OFF   = H_OFF   + (size_t)ROW_CAP * D_HID * 2;  // +41.9 MB
    const size_t W1B_OFF = Y_OFF   + (size_t)ROW_CAP * D_OUT * 4;  // +21.0 MB
    const size_t W2B_OFF = W1B_OFF + (size_t)NEXP * D_HID * D_IN * 2;  // +67.1 MB
    unsigned short* Xe  = (unsigned short*)(ws + XE_OFF);
    unsigned short* H   = (unsigned short*)(ws + H_OFF);
    float*          Y   = (float*)(ws + Y_OFF);
    unsigned short* W1b = (unsigned short*)(ws + W1B_OFF);
    unsigned short* W2b = (unsigned short*)(ws + W2B_OFF);

    hipMemsetAsync(d_ws, 0, 128, stream);                       // counts+cursor
    hipMemsetAsync(ws + Y_OFF, 0, (size_t)ROW_CAP * D_OUT * 4, stream);  // Y

    const int W1_N4 = NEXP * D_HID * D_IN / 4;
    const int W2_N4 = NEXP * D_OUT * D_HID / 4;
    convert_w<<<4096, 256, 0, stream>>>((const float4*)W1, (uint2*)W1b, W1_N4);
    convert_w<<<4096, 256, 0, stream>>>((const float4*)W2, (uint2*)W2b, W2_N4);

    gate_kernel<<<N_TOK / 4, 256, 0, stream>>>(x, gw, gb, topi, topw, counts);
    scan_kernel<<<1, 64, 0, stream>>>(counts, offsets, cursor);
    gather_kernel<<<N_TOK * TOPK, 64, 0, stream>>>(x, topi, cursor, slot_of, Xe);

    // GEMM1: H = relu(Xe @ W1^T + b1), bf16 out
    moe_gemm<D_IN, D_HID, 1, true, 1><<<dim3(D_HID / 128, 16, NEXP), 256, 0, stream>>>(
        Xe, W1b, b1, (void*)H, counts, offsets);
    // GEMM2: Y += H @ W2^T (split-K=4, fp32 atomic partials; b2 in combine)
    moe_gemm<D_HID, D_OUT, 4, false, 2><<<dim3(D_OUT / 128, 16, NEXP * 4), 256, 0, stream>>>(
        H, W2b, b2, (void*)Y, counts, offsets);

    combine_kernel<<<N_TOK, 256, 0, stream>>>(Y, slot_of, topi, topw, b2, out);
}